// Round 6
// baseline (202.352 us; speedup 1.0000x reference)
//
#include <hip/hip_runtime.h>
#include <hip/hip_bf16.h>

#define D 64
#define CLAMP_V -10000.0f
#define SBSHIFT 9           // super-bucket = 512 nodes (dst >> 9)
#define SBN 512
#define MAXSB 256           // static bound; runtime nbSB = ceil(100k/512) = 196
#define HCHUNK 4096         // edges per hist slice (inside prep)
#define SCHUNK 4096         // edges per scatter block
#define SORT_THREADS 1024   // sb_sort block width (196 blocks only -> go wide)

typedef __bf16 bf16x4 __attribute__((ext_vector_type(4)));
typedef __bf16 bf16x8 __attribute__((ext_vector_type(8)));
typedef float floatx4 __attribute__((ext_vector_type(4)));
typedef unsigned short u16x2 __attribute__((ext_vector_type(2)));
typedef short s16x2 __attribute__((ext_vector_type(2)));

// packed max of 2x u16 (v_pk_max_u16)
__device__ __forceinline__ unsigned pkmax(unsigned a, unsigned b) {
    u16x2 r = __builtin_elementwise_max(__builtin_bit_cast(u16x2, a),
                                        __builtin_bit_cast(u16x2, b));
    return __builtin_bit_cast(unsigned, r);
}
__device__ __forceinline__ uint4 pkmax4(uint4 a, uint4 b) {
    uint4 r;
    r.x = pkmax(a.x, b.x); r.y = pkmax(a.y, b.y);
    r.z = pkmax(a.z, b.z); r.w = pkmax(a.w, b.w);
    return r;
}
// packed ord-encode of 2x bf16 (monotone u16): pos -> |0x8000, neg -> ~
__device__ __forceinline__ unsigned pk_ord_encode(unsigned g) {
    s16x2 t = __builtin_bit_cast(s16x2, g) >> 15;
    unsigned m = __builtin_bit_cast(unsigned, t) & 0x7FFF7FFFu;
    return g ^ (m | 0x80008000u);
}
__device__ __forceinline__ unsigned pk_ord_decode(unsigned e) {
    s16x2 t = __builtin_bit_cast(s16x2, e) >> 15;
    unsigned m = (~__builtin_bit_cast(unsigned, t)) & 0x7FFF7FFFu;
    return e ^ (m | 0x80008000u);
}
// decode running max + self row (both ord-encoded), subtract, clamp, pack bf16
__device__ __forceinline__ unsigned seg_finish2(unsigned encm, unsigned encs) {
    unsigned raw = pk_ord_decode(encm);          // empty run (encm==0) -> NaN halves
    unsigned xr  = pk_ord_decode(encs);
    float v0 = __uint_as_float(raw << 16);
    float v1 = __uint_as_float(raw & 0xFFFF0000u);
    float x0 = __uint_as_float(xr << 16);
    float x1 = __uint_as_float(xr & 0xFFFF0000u);
    float r0 = v0 - x0; r0 = (r0 >= CLAMP_V) ? r0 : 0.0f;   // NaN -> 0
    float r1 = v1 - x1; r1 = (r1 >= CLAMP_V) ? r1 : 0.0f;
    __bf16 b0 = (__bf16)r0, b1 = (__bf16)r1;
    return ((unsigned)__builtin_bit_cast(unsigned short, b1) << 16)
         |  (unsigned)__builtin_bit_cast(unsigned short, b0);
}

// ---------- pass 0: fp32->bf16 conversion + 4-plane encoded copy + hist + W ----
// nfenc is stored as 4 COLUMN PLANES: plane q holds the 32-B quarter-slice
// [q*32, q*32+32) of every row, contiguously (3.2 MB/plane). Plane
// separation (not interleaved) is required so a quarter's working set is
// 3.2 MB of whole cache lines -> fits one XCD's 4-MB L2 in seg_direct.
__global__ __launch_bounds__(256) void prep_kernel(
        const float* __restrict__ nf, __bf16* __restrict__ nf16,
        unsigned* __restrict__ nfenc, int n4, int nN,
        const int* __restrict__ dst, unsigned* __restrict__ ghist,
        int nE, int nbSB,
        const float* __restrict__ W, __bf16* __restrict__ wfrag,
        int histBlocks, int wBlock) {
    __shared__ unsigned h[MAXSB];
    int blk = blockIdx.x, t = threadIdx.x;
    int i = blk * 256 + t;
    if (i < n4) {
        float4 v = ((const float4*)nf)[i];
        __bf16 b0 = (__bf16)v.x, b1 = (__bf16)v.y;
        __bf16 b2 = (__bf16)v.z, b3 = (__bf16)v.w;
        bf16x4 o = { b0, b1, b2, b3 };
        ((bf16x4*)nf16)[i] = o;
        // pre-ord-encoded copy, plane layout
        unsigned d0 = ((unsigned)__builtin_bit_cast(unsigned short, b1) << 16)
                    |  (unsigned)__builtin_bit_cast(unsigned short, b0);
        unsigned d1 = ((unsigned)__builtin_bit_cast(unsigned short, b3) << 16)
                    |  (unsigned)__builtin_bit_cast(unsigned short, b2);
        uint2 e; e.x = pk_ord_encode(d0); e.y = pk_ord_encode(d1);
        int r = i >> 4, j = i & 15;             // 16 uint2-chunks per 128-B row
        int q = j >> 2, w = j & 3;              // quarter, slot within quarter
        ((uint2*)nfenc)[(size_t)q * nN * 4 + (size_t)r * 4 + w] = e;
    }
    if (blk < histBlocks) {
        if (t < MAXSB) h[t] = 0;
        __syncthreads();
        int e0 = blk * HCHUNK;
        int ec = nE - e0; if (ec > HCHUNK) ec = HCHUNK;
        for (int k = t; k < ec; k += 256) atomicAdd(&h[dst[e0 + k] >> SBSHIFT], 1u);
        __syncthreads();
        if (t < (unsigned)nbSB && h[t]) atomicAdd(&ghist[t], h[t]);
    }
    if (blk == wBlock) {
        // W[k][n] fp32 -> bf16 in MFMA-fragment order:
        // fidx = ((ks*4+c)*64 + quad*16+l16)*8 + j, k=ks*32+quad*8+j, n=c*16+l16
        for (int idx = t; idx < 2 * D * D; idx += 256) {
            int k = idx >> 6, n = idx & 63;
            int ks = k >> 5, r = k & 31, quad = r >> 3, j = r & 7;
            int c = n >> 4, l16 = n & 15;
            int fidx = (((ks * 4 + c) * 64) + quad * 16 + l16) * 8 + j;
            wfrag[fidx] = (__bf16)W[idx];
        }
    }
}

// ---------- pass B: exclusive scan over nbSB (single block) ----------
__global__ __launch_bounds__(256) void scan_sb(
        const unsigned* __restrict__ ghist, unsigned* __restrict__ base,
        unsigned* __restrict__ cursor, int nbSB) {
    __shared__ unsigned ts[256];
    int t = threadIdx.x;
    unsigned v = (t < nbSB) ? ghist[t] : 0u;
    ts[t] = v; __syncthreads();
    for (int off = 1; off < 256; off <<= 1) {
        unsigned x = (t >= off) ? ts[t - off] : 0u;
        __syncthreads();
        ts[t] += x;
        __syncthreads();
    }
    if (t < nbSB) {
        unsigned ex = ts[t] - v;
        base[t] = ex; cursor[t] = ex;
        if (t == nbSB - 1) base[nbSB] = ts[t];
    }
}

// ---------- pass C: bin edges into 196 super-buckets, coalesced flush ------
// entry = (dst&511)<<17 | src  (src < 2^17)
__global__ __launch_bounds__(256) void sb_scatter(
        const int* __restrict__ src, const int* __restrict__ dst,
        unsigned* __restrict__ cursor, unsigned* __restrict__ packed,
        int nE, int nbSB) {
    __shared__ unsigned cop[MAXSB];            // cnt low16, off high16
    __shared__ unsigned short lb16[MAXSB];
    __shared__ unsigned gbase[MAXSB];
    __shared__ unsigned payload[SCHUNK];       // 16 KB, bucket-sorted entries
    __shared__ unsigned char sbid[SCHUNK];     // 4 KB
    __shared__ unsigned ts[256];
    int t = threadIdx.x;
    int e0 = blockIdx.x * SCHUNK;
    int ec = nE - e0; if (ec > SCHUNK) ec = SCHUNK;

    if (t < MAXSB) cop[t] = 0;
    __syncthreads();
    for (int i = t; i < ec; i += 256)
        atomicAdd(&cop[dst[e0 + i] >> SBSHIFT], 1u);
    __syncthreads();
    unsigned c = (t < nbSB) ? (cop[t] & 0xFFFFu) : 0u;
    ts[t] = c; __syncthreads();
    for (int o = 1; o < 256; o <<= 1) {
        unsigned x = (t >= o) ? ts[t - o] : 0u;
        __syncthreads();
        ts[t] += x;
        __syncthreads();
    }
    if (t < nbSB) {
        lb16[t] = (unsigned short)(ts[t] - c);
        if (c) gbase[t] = atomicAdd(&cursor[t], c);
    }
    __syncthreads();
    for (int i = t; i < ec; i += 256) {
        int e = e0 + i;
        int d = dst[e];
        int b = d >> SBSHIFT;
        unsigned p = atomicAdd(&cop[b], 0x10000u) >> 16;
        unsigned pos = (unsigned)lb16[b] + p;
        payload[pos] = ((unsigned)(d & (SBN - 1)) << 17) | (unsigned)src[e];
        sbid[pos] = (unsigned char)b;
    }
    __syncthreads();
    // flush: payload is bucket-sorted; same-bucket entries are adjacent ->
    // runs of ~21 entries -> line-coalesced bursts
    for (int i = t; i < ec; i += 256) {
        unsigned b = sbid[i];
        packed[gbase[b] + ((unsigned)i - (unsigned)lb16[b])] = payload[i];
    }
}

// ---------- pass C2: per-SB counting sort to node order + CSR nodestart ----
// Only 196 blocks exist (one per SB) -> run them 1024 wide: 4x fewer
// strided iterations of dependent atomic work per thread vs 256 wide.
__global__ __launch_bounds__(SORT_THREADS) void sb_sort(
        const unsigned* __restrict__ packed1, const unsigned* __restrict__ base,
        unsigned* __restrict__ packed2, unsigned* __restrict__ nodestart,
        int nN) {
    __shared__ unsigned cnt[SBN];               // 2 KB (counts, then cursors)
    __shared__ unsigned ts[SBN];                // 2 KB scan buffer
    int sb = blockIdx.x, t = threadIdx.x;
    unsigned beg = base[sb], end = base[sb + 1];
    if (t < SBN) cnt[t] = 0;
    __syncthreads();
    for (unsigned i = beg + t; i < end; i += SORT_THREADS)
        atomicAdd(&cnt[packed1[i] >> 17], 1u);
    __syncthreads();
    unsigned s = (t < SBN) ? cnt[t] : 0u;
    if (t < SBN) ts[t] = s;
    __syncthreads();
    for (int o = 1; o < SBN; o <<= 1) {
        unsigned x = 0;
        if (t < SBN && t >= o) x = ts[t - o];
        __syncthreads();
        if (t < SBN) ts[t] += x;
        __syncthreads();
    }
    if (t < SBN) {
        unsigned ex = ts[t] - s;                // exclusive prefix
        cnt[t] = ex;                            // reuse as scatter cursor
        int n0 = sb * SBN;
        if (n0 + t <= nN) nodestart[n0 + t] = beg + ex;
    }
    __syncthreads();
    // scatter to node-sorted order (writes confined to hot 32 KB window)
    for (unsigned i = beg + t; i < end; i += SORT_THREADS) {
        unsigned e = packed1[i];
        unsigned p = atomicAdd(&cnt[e >> 17], 1u);
        packed2[beg + p] = e & 0x1FFFFu;        // src only; position encodes node
    }
}

// ---------- pass D: XCD-pinned quarter-plane segmax ----------
// Quarter q = (blockIdx%8)>>1 pins each feature-quarter to one XCD PAIR:
// with the empirical round-robin block->XCD mapping, each XCD's 4-MB L2
// caches exactly one 3.2-MB plane for the whole kernel -> gathers become
// L2 hits instead of L3-service-rate-bound (the R2-R4 ~6.4 TB/s wall).
// Correctness does NOT depend on the mapping (any block can run any q).
// Wave = 32 groups x 2 lanes; group owns one node, lane owns 16 B of the
// 32-B quarter slice. packed2 runs for 32 consecutive nodes are contiguous
// (~2 KB window/wave). No shuffles, no LDS, no cross-lane reduction.
// deg==0 -> acc 0 -> ord-decode NaN -> clamp 0.
__global__ __launch_bounds__(256) void seg_direct(
        const uint4* __restrict__ plane,        // 4 planes, nN*2 uint4 each
        const unsigned* __restrict__ packed2,   // node-sorted src indices
        const unsigned* __restrict__ nodestart,
        uint4* __restrict__ agg4,               // bf16 agg, row-major 8 uint4/row
        int nN) {
    int bid = blockIdx.x;
    int q = (bid & 7) >> 1;                     // quarter pinned to XCD pair
    int chunk = (bid >> 3) * 2 + (bid & 1);     // node chunk within quarter
    int t = threadIdx.x;
    int ln = t & 63;
    int grp = ln >> 1;                          // node slot within wave (0..31)
    int h = ln & 1;                             // 16-B half of 32-B slice
    int n = chunk * 128 + (t >> 6) * 32 + grp;
    if (n >= nN) return;
    unsigned rb = nodestart[n], re = nodestart[n + 1];
    unsigned deg = re - rb;
    const uint4* pq = plane + (size_t)q * nN * 2 + h;
    // identity 0 is below every encoded real bf16 (min real enc = 0x0080)
    uint4 a0 = {0,0,0,0}, a1 = {0,0,0,0}, a2 = {0,0,0,0}, a3 = {0,0,0,0};
    unsigned i = 0;
    for (; i + 8 <= deg; i += 8) {              // 8 idx + 8 gathers in flight
        unsigned e0 = packed2[rb + i];
        unsigned e1 = packed2[rb + i + 1];
        unsigned e2 = packed2[rb + i + 2];
        unsigned e3 = packed2[rb + i + 3];
        unsigned e4 = packed2[rb + i + 4];
        unsigned e5 = packed2[rb + i + 5];
        unsigned e6 = packed2[rb + i + 6];
        unsigned e7 = packed2[rb + i + 7];
        uint4 g0 = pq[(size_t)e0 * 2];
        uint4 g1 = pq[(size_t)e1 * 2];
        uint4 g2 = pq[(size_t)e2 * 2];
        uint4 g3 = pq[(size_t)e3 * 2];
        uint4 g4 = pq[(size_t)e4 * 2];
        uint4 g5 = pq[(size_t)e5 * 2];
        uint4 g6 = pq[(size_t)e6 * 2];
        uint4 g7 = pq[(size_t)e7 * 2];
        a0 = pkmax4(a0, g0);
        a1 = pkmax4(a1, g1);
        a2 = pkmax4(a2, g2);
        a3 = pkmax4(a3, g3);
        a0 = pkmax4(a0, g4);
        a1 = pkmax4(a1, g5);
        a2 = pkmax4(a2, g6);
        a3 = pkmax4(a3, g7);
    }
    for (; i + 4 <= deg; i += 4) {
        unsigned e0 = packed2[rb + i];
        unsigned e1 = packed2[rb + i + 1];
        unsigned e2 = packed2[rb + i + 2];
        unsigned e3 = packed2[rb + i + 3];
        uint4 g0 = pq[(size_t)e0 * 2];
        uint4 g1 = pq[(size_t)e1 * 2];
        uint4 g2 = pq[(size_t)e2 * 2];
        uint4 g3 = pq[(size_t)e3 * 2];
        a0 = pkmax4(a0, g0);
        a1 = pkmax4(a1, g1);
        a2 = pkmax4(a2, g2);
        a3 = pkmax4(a3, g3);
    }
    for (; i < deg; ++i) {
        unsigned e0 = packed2[rb + i];
        a0 = pkmax4(a0, pq[(size_t)e0 * 2]);
    }
    uint4 m = pkmax4(pkmax4(a0, a1), pkmax4(a2, a3));
    uint4 es = pq[(size_t)n * 2];               // self row quarter (encoded)
    uint4 o;
    o.x = seg_finish2(m.x, es.x);
    o.y = seg_finish2(m.y, es.y);
    o.z = seg_finish2(m.z, es.z);
    o.w = seg_finish2(m.w, es.w);
    agg4[(size_t)n * 8 + q * 2 + h] = o;        // 32-B slice of row-major agg
}

// ---------- pass E: MFMA MLP; W from frag-order buffer ----------
__global__ __launch_bounds__(256) void node_mlp_mfma(
        const __bf16* __restrict__ nf16,
        const __bf16* __restrict__ agg16,
        float* __restrict__ out,
        const __bf16* __restrict__ wfrag,
        const float* __restrict__ bias,
        int nTiles, int nN) {
    int lane = threadIdx.x & 63;
    int quad = lane >> 4;
    int l16  = lane & 15;
    int waveGlobal = blockIdx.x * 4 + (threadIdx.x >> 6);
    int nWaves = gridDim.x * 4;

    bf16x8 bfrag[4][4];
    #pragma unroll
    for (int c = 0; c < 4; ++c)
        #pragma unroll
        for (int ks = 0; ks < 4; ++ks)
            bfrag[c][ks] = *(const bf16x8*)(wfrag + ((size_t)((ks * 4 + c) * 64 + lane)) * 8);
    float bv[4];
    #pragma unroll
    for (int c = 0; c < 4; ++c) bv[c] = bias[c * 16 + l16];

    for (int t = waveGlobal; t < nTiles; t += nWaves) {
        int n0 = t * 16;
        int rowA = n0 + l16;
        if (rowA >= nN) rowA = nN - 1;
        const __bf16* nfr = nf16  + (size_t)rowA * D;
        const __bf16* agr = agg16 + (size_t)rowA * D;

        floatx4 acc[4] = {{0,0,0,0},{0,0,0,0},{0,0,0,0},{0,0,0,0}};
        #pragma unroll
        for (int ks = 0; ks < 4; ++ks) {
            const __bf16* p = (ks < 2) ? (nfr + ks * 32 + quad * 8)
                                       : (agr + (ks - 2) * 32 + quad * 8);
            bf16x8 a = *(const bf16x8*)p;
            #pragma unroll
            for (int c = 0; c < 4; ++c)
                acc[c] = __builtin_amdgcn_mfma_f32_16x16x32_bf16(
                             a, bfrag[c][ks], acc[c], 0, 0, 0);
        }
        #pragma unroll
        for (int r = 0; r < 4; ++r) {
            int row = n0 + quad * 4 + r;
            if (row < nN) {
                #pragma unroll
                for (int c = 0; c < 4; ++c) {
                    float vv = acc[c][r] + bv[c];
                    out[(size_t)row * D + c * 16 + l16] = fmaxf(vv, 0.0f);
                }
            }
        }
    }
}

extern "C" void kernel_launch(void* const* d_in, const int* in_sizes, int n_in,
                              void* d_out, int out_size, void* d_ws, size_t ws_size,
                              hipStream_t stream) {
    const float* nf  = (const float*)d_in[0];
    const int*   src = (const int*)d_in[1];
    const int*   dst = (const int*)d_in[2];
    const float* W   = (const float*)d_in[3];
    const float* b   = (const float*)d_in[4];
    float* out = (float*)d_out;

    int nN = in_sizes[0] / D;
    int nE = in_sizes[1];
    int nbSB = (nN + SBN - 1) / SBN;            // 196

    // ws layout
    char* wsb = (char*)d_ws;
    size_t nfB  = (((size_t)nN * D * 2) + 255) & ~(size_t)255;  // 12.8 MB
    size_t pkB  = (((size_t)nE * 4)     + 255) & ~(size_t)255;  // 6.4 MB
    __bf16*   nf16   = (__bf16*)wsb;
    __bf16*   agg16  = (__bf16*)(wsb + nfB);
    unsigned* packed1 = (unsigned*)(wsb + 2 * nfB);
    unsigned* ghist  = (unsigned*)(wsb + 2 * nfB + pkB);
    unsigned* base   = (unsigned*)(wsb + 2 * nfB + pkB + 4 * MAXSB);
    unsigned* cursor = (unsigned*)(wsb + 2 * nfB + pkB + 4 * MAXSB + 4 * (MAXSB + 2));
    __bf16*   wfrag  = (__bf16*)(wsb + 2 * nfB + pkB + 4 * MAXSB + 8 * (MAXSB + 2));
    unsigned* nodestart = (unsigned*)(wsb + 2 * nfB + pkB + 4 * MAXSB
                                      + 8 * (MAXSB + 2) + 32768);
    // packed2 + nfenc live in d_out (25.6 MB): both consumed by seg_direct
    // before the MLP writes out. packed2 at [0, 6.4M), nfenc at [6.4M, 19.2M).
    unsigned* packed2 = (unsigned*)d_out;
    unsigned* nfenc   = (unsigned*)((char*)d_out + pkB);

    hipMemsetAsync(ghist, 0, (size_t)nbSB * 4, stream);

    int n4 = nN * D / 4;                        // 1.6M
    int convBlocks = (n4 + 255) / 256;          // 6250
    int histBlocks = (nE + HCHUNK - 1) / HCHUNK;// 391
    int gridPrep = convBlocks > histBlocks ? convBlocks : histBlocks;
    prep_kernel<<<gridPrep, 256, 0, stream>>>(nf, nf16, nfenc, n4, nN, dst, ghist,
                                              nE, nbSB, W, wfrag,
                                              histBlocks, gridPrep - 1);

    scan_sb<<<1, 256, 0, stream>>>(ghist, base, cursor, nbSB);

    int nbS = (nE + SCHUNK - 1) / SCHUNK;       // 391
    sb_scatter<<<nbS, 256, 0, stream>>>(src, dst, cursor, packed1, nE, nbSB);

    sb_sort<<<nbSB, SORT_THREADS, 0, stream>>>(packed1, base, packed2,
                                               nodestart, nN);

    // grid = 8 * pairs: quarter = (bid%8)>>1, chunk = (bid>>3)*2 + (bid&1)
    int chunks = (nN + 127) / 128;              // 782 (128 nodes per block)
    int pairs = (chunks + 1) / 2;               // 391
    seg_direct<<<pairs * 8, 256, 0, stream>>>(
        (const uint4*)nfenc, packed2, nodestart, (uint4*)agg16, nN);

    int nTiles = (nN + 15) / 16;
    node_mlp_mfma<<<768, 256, 0, stream>>>(nf16, agg16, out, wfrag, b, nTiles, nN);
}

// Round 7
// 177.241 us; speedup vs baseline: 1.1417x; 1.1417x over previous
//
#include <hip/hip_runtime.h>
#include <hip/hip_bf16.h>

#define D 64
#define CLAMP_V -10000.0f
#define SBSHIFT 9           // super-bucket = 512 nodes (dst >> 9)
#define SBN 512
#define MAXSB 256           // static bound; runtime nbSB = ceil(100k/512) = 196
#define HCHUNK 4096         // edges per hist slice (inside prep)
#define SCHUNK 4096         // edges per scatter block
#define SORT_THREADS 1024   // sb_sort block width (196 blocks only -> go wide)

typedef __bf16 bf16x4 __attribute__((ext_vector_type(4)));
typedef __bf16 bf16x8 __attribute__((ext_vector_type(8)));
typedef float floatx4 __attribute__((ext_vector_type(4)));
typedef unsigned short u16x2 __attribute__((ext_vector_type(2)));
typedef short s16x2 __attribute__((ext_vector_type(2)));

// packed max of 2x u16 (v_pk_max_u16)
__device__ __forceinline__ unsigned pkmax(unsigned a, unsigned b) {
    u16x2 r = __builtin_elementwise_max(__builtin_bit_cast(u16x2, a),
                                        __builtin_bit_cast(u16x2, b));
    return __builtin_bit_cast(unsigned, r);
}
__device__ __forceinline__ uint4 pkmax4(uint4 a, uint4 b) {
    uint4 r;
    r.x = pkmax(a.x, b.x); r.y = pkmax(a.y, b.y);
    r.z = pkmax(a.z, b.z); r.w = pkmax(a.w, b.w);
    return r;
}
// packed ord-encode of 2x bf16 (monotone u16): pos -> |0x8000, neg -> ~
__device__ __forceinline__ unsigned pk_ord_encode(unsigned g) {
    s16x2 t = __builtin_bit_cast(s16x2, g) >> 15;
    unsigned m = __builtin_bit_cast(unsigned, t) & 0x7FFF7FFFu;
    return g ^ (m | 0x80008000u);
}
__device__ __forceinline__ unsigned pk_ord_decode(unsigned e) {
    s16x2 t = __builtin_bit_cast(s16x2, e) >> 15;
    unsigned m = (~__builtin_bit_cast(unsigned, t)) & 0x7FFF7FFFu;
    return e ^ (m | 0x80008000u);
}
// decode running max + self row (both ord-encoded), subtract, clamp, pack bf16
__device__ __forceinline__ unsigned seg_finish2(unsigned encm, unsigned encs) {
    unsigned raw = pk_ord_decode(encm);          // empty run (encm==0) -> NaN halves
    unsigned xr  = pk_ord_decode(encs);
    float v0 = __uint_as_float(raw << 16);
    float v1 = __uint_as_float(raw & 0xFFFF0000u);
    float x0 = __uint_as_float(xr << 16);
    float x1 = __uint_as_float(xr & 0xFFFF0000u);
    float r0 = v0 - x0; r0 = (r0 >= CLAMP_V) ? r0 : 0.0f;   // NaN -> 0
    float r1 = v1 - x1; r1 = (r1 >= CLAMP_V) ? r1 : 0.0f;
    __bf16 b0 = (__bf16)r0, b1 = (__bf16)r1;
    return ((unsigned)__builtin_bit_cast(unsigned short, b1) << 16)
         |  (unsigned)__builtin_bit_cast(unsigned short, b0);
}

// ---------- pass 0: fp32 -> ord-encoded bf16 (single buffer) + SB hist + W ----
// Only nfenc is materialized (row-major, 32 dwords/row). The MLP decodes
// its A-fragments from nfenc in-register (12 VALU/fragment, memory-bound
// kernel -> free), saving the 12.8 MB nf16 write R4 had.
__global__ __launch_bounds__(256) void prep_kernel(
        const float* __restrict__ nf, unsigned* __restrict__ nfenc, int n4,
        const int* __restrict__ dst, unsigned* __restrict__ ghist,
        int nE, int nbSB,
        const float* __restrict__ W, __bf16* __restrict__ wfrag,
        int histBlocks, int wBlock) {
    __shared__ unsigned h[MAXSB];
    int blk = blockIdx.x, t = threadIdx.x;
    int i = blk * 256 + t;
    if (i < n4) {
        float4 v = ((const float4*)nf)[i];
        __bf16 b0 = (__bf16)v.x, b1 = (__bf16)v.y;
        __bf16 b2 = (__bf16)v.z, b3 = (__bf16)v.w;
        unsigned d0 = ((unsigned)__builtin_bit_cast(unsigned short, b1) << 16)
                    |  (unsigned)__builtin_bit_cast(unsigned short, b0);
        unsigned d1 = ((unsigned)__builtin_bit_cast(unsigned short, b3) << 16)
                    |  (unsigned)__builtin_bit_cast(unsigned short, b2);
        uint2 e; e.x = pk_ord_encode(d0); e.y = pk_ord_encode(d1);
        ((uint2*)nfenc)[i] = e;
    }
    if (blk < histBlocks) {
        if (t < MAXSB) h[t] = 0;
        __syncthreads();
        int e0 = blk * HCHUNK;
        int ec = nE - e0; if (ec > HCHUNK) ec = HCHUNK;
        for (int k = t; k < ec; k += 256) atomicAdd(&h[dst[e0 + k] >> SBSHIFT], 1u);
        __syncthreads();
        if (t < (unsigned)nbSB && h[t]) atomicAdd(&ghist[t], h[t]);
    }
    if (blk == wBlock) {
        // W[k][n] fp32 -> bf16 in MFMA-fragment order:
        // fidx = ((ks*4+c)*64 + quad*16+l16)*8 + j, k=ks*32+quad*8+j, n=c*16+l16
        for (int idx = t; idx < 2 * D * D; idx += 256) {
            int k = idx >> 6, n = idx & 63;
            int ks = k >> 5, r = k & 31, quad = r >> 3, j = r & 7;
            int c = n >> 4, l16 = n & 15;
            int fidx = (((ks * 4 + c) * 64) + quad * 16 + l16) * 8 + j;
            wfrag[fidx] = (__bf16)W[idx];
        }
    }
}

// ---------- pass B: exclusive scan over nbSB (single block) ----------
__global__ __launch_bounds__(256) void scan_sb(
        const unsigned* __restrict__ ghist, unsigned* __restrict__ base,
        unsigned* __restrict__ cursor, int nbSB) {
    __shared__ unsigned ts[256];
    int t = threadIdx.x;
    unsigned v = (t < nbSB) ? ghist[t] : 0u;
    ts[t] = v; __syncthreads();
    for (int off = 1; off < 256; off <<= 1) {
        unsigned x = (t >= off) ? ts[t - off] : 0u;
        __syncthreads();
        ts[t] += x;
        __syncthreads();
    }
    if (t < nbSB) {
        unsigned ex = ts[t] - v;
        base[t] = ex; cursor[t] = ex;
        if (t == nbSB - 1) base[nbSB] = ts[t];
    }
}

// ---------- pass C: bin edges into 196 super-buckets, coalesced flush ------
// entry = (dst&511)<<17 | src  (src < 2^17)
__global__ __launch_bounds__(256) void sb_scatter(
        const int* __restrict__ src, const int* __restrict__ dst,
        unsigned* __restrict__ cursor, unsigned* __restrict__ packed,
        int nE, int nbSB) {
    __shared__ unsigned cop[MAXSB];            // cnt low16, off high16
    __shared__ unsigned short lb16[MAXSB];
    __shared__ unsigned gbase[MAXSB];
    __shared__ unsigned payload[SCHUNK];       // 16 KB, bucket-sorted entries
    __shared__ unsigned char sbid[SCHUNK];     // 4 KB
    __shared__ unsigned ts[256];
    int t = threadIdx.x;
    int e0 = blockIdx.x * SCHUNK;
    int ec = nE - e0; if (ec > SCHUNK) ec = SCHUNK;

    if (t < MAXSB) cop[t] = 0;
    __syncthreads();
    for (int i = t; i < ec; i += 256)
        atomicAdd(&cop[dst[e0 + i] >> SBSHIFT], 1u);
    __syncthreads();
    unsigned c = (t < nbSB) ? (cop[t] & 0xFFFFu) : 0u;
    ts[t] = c; __syncthreads();
    for (int o = 1; o < 256; o <<= 1) {
        unsigned x = (t >= o) ? ts[t - o] : 0u;
        __syncthreads();
        ts[t] += x;
        __syncthreads();
    }
    if (t < nbSB) {
        lb16[t] = (unsigned short)(ts[t] - c);
        if (c) gbase[t] = atomicAdd(&cursor[t], c);
    }
    __syncthreads();
    for (int i = t; i < ec; i += 256) {
        int e = e0 + i;
        int d = dst[e];
        int b = d >> SBSHIFT;
        unsigned p = atomicAdd(&cop[b], 0x10000u) >> 16;
        unsigned pos = (unsigned)lb16[b] + p;
        payload[pos] = ((unsigned)(d & (SBN - 1)) << 17) | (unsigned)src[e];
        sbid[pos] = (unsigned char)b;
    }
    __syncthreads();
    // flush: payload is bucket-sorted; same-bucket entries are adjacent ->
    // runs of ~21 entries -> line-coalesced bursts
    for (int i = t; i < ec; i += 256) {
        unsigned b = sbid[i];
        packed[gbase[b] + ((unsigned)i - (unsigned)lb16[b])] = payload[i];
    }
}

// ---------- pass C2: per-SB counting sort to node order + CSR nodestart ----
// Only 196 blocks exist (one per SB) -> run them 1024 wide: 4x fewer
// strided iterations of dependent atomic work per thread vs 256 wide.
__global__ __launch_bounds__(SORT_THREADS) void sb_sort(
        const unsigned* __restrict__ packed1, const unsigned* __restrict__ base,
        unsigned* __restrict__ packed2, unsigned* __restrict__ nodestart,
        int nN) {
    __shared__ unsigned cnt[SBN];               // 2 KB (counts, then cursors)
    __shared__ unsigned ts[SBN];                // 2 KB scan buffer
    int sb = blockIdx.x, t = threadIdx.x;
    unsigned beg = base[sb], end = base[sb + 1];
    if (t < SBN) cnt[t] = 0;
    __syncthreads();
    for (unsigned i = beg + t; i < end; i += SORT_THREADS)
        atomicAdd(&cnt[packed1[i] >> 17], 1u);
    __syncthreads();
    unsigned s = (t < SBN) ? cnt[t] : 0u;
    if (t < SBN) ts[t] = s;
    __syncthreads();
    for (int o = 1; o < SBN; o <<= 1) {
        unsigned x = 0;
        if (t < SBN && t >= o) x = ts[t - o];
        __syncthreads();
        if (t < SBN) ts[t] += x;
        __syncthreads();
    }
    if (t < SBN) {
        unsigned ex = ts[t] - s;                // exclusive prefix
        cnt[t] = ex;                            // reuse as scatter cursor
        int n0 = sb * SBN;
        if (n0 + t <= nN) nodestart[n0 + t] = beg + ex;
    }
    __syncthreads();
    // scatter to node-sorted order (writes confined to hot 32 KB window)
    for (unsigned i = beg + t; i < end; i += SORT_THREADS) {
        unsigned e = packed1[i];
        unsigned p = atomicAdd(&cnt[e >> 17], 1u);
        packed2[beg + p] = e & 0x1FFFFu;        // src only; position encodes node
    }
}

// ---------- pass D: group-parallel segmax over CSR runs (R4 form) ----------
// wave = 8 groups x 8 lanes; group g owns node n0+g; lane owns a 16-B
// column slice of the 128-B feature row. The 8 lanes of a group read the
// SAME packed2 dword (same-address lanes coalesce to one request + L1
// broadcast). Each lane pkmax4-accumulates its own slice: NO cross-lane
// reduction, wave-coalesced final store. 8 nodes advance in parallel per
// wave; unroll-8 keeps 8 independent full-row gathers in flight per lane.
// ONE pass over the edge stream, full 128-B row per gather instruction --
// the R6 quarter-plane split (4x index stream, 4x instructions, 32-B
// half-line gathers) regressed 30->53 us; do not re-split. deg==0 ->
// acc 0 -> ord-decode NaN -> clamp 0.
__global__ __launch_bounds__(256) void seg_direct(
        const uint4* __restrict__ enc4,         // pre-encoded rows, 8 uint4/row
        const unsigned* __restrict__ packed2,   // node-sorted src indices
        const unsigned* __restrict__ nodestart,
        uint4* __restrict__ agg4,               // bf16 agg, 8 uint4/row
        int nN) {
    int t = threadIdx.x;
    int ln = t & 63;
    int grp = ln >> 3;                          // node slot within wave (0..7)
    int col = ln & 7;                           // uint4 column within row
    int n = blockIdx.x * 32 + (t >> 6) * 8 + grp;
    if (n >= nN) return;
    unsigned rb = nodestart[n], re = nodestart[n + 1];
    unsigned deg = re - rb;
    const uint4* ec = enc4 + col;
    // identity 0 is below every encoded real bf16 (min real enc = 0x0080)
    uint4 a0 = {0,0,0,0}, a1 = {0,0,0,0}, a2 = {0,0,0,0}, a3 = {0,0,0,0};
    unsigned i = 0;
    for (; i + 8 <= deg; i += 8) {              // 8 idx + 8 gathers in flight
        unsigned e0 = packed2[rb + i];
        unsigned e1 = packed2[rb + i + 1];
        unsigned e2 = packed2[rb + i + 2];
        unsigned e3 = packed2[rb + i + 3];
        unsigned e4 = packed2[rb + i + 4];
        unsigned e5 = packed2[rb + i + 5];
        unsigned e6 = packed2[rb + i + 6];
        unsigned e7 = packed2[rb + i + 7];
        uint4 g0 = ec[(size_t)e0 * 8];
        uint4 g1 = ec[(size_t)e1 * 8];
        uint4 g2 = ec[(size_t)e2 * 8];
        uint4 g3 = ec[(size_t)e3 * 8];
        uint4 g4 = ec[(size_t)e4 * 8];
        uint4 g5 = ec[(size_t)e5 * 8];
        uint4 g6 = ec[(size_t)e6 * 8];
        uint4 g7 = ec[(size_t)e7 * 8];
        a0 = pkmax4(a0, g0);
        a1 = pkmax4(a1, g1);
        a2 = pkmax4(a2, g2);
        a3 = pkmax4(a3, g3);
        a0 = pkmax4(a0, g4);
        a1 = pkmax4(a1, g5);
        a2 = pkmax4(a2, g6);
        a3 = pkmax4(a3, g7);
    }
    for (; i + 4 <= deg; i += 4) {
        unsigned e0 = packed2[rb + i];
        unsigned e1 = packed2[rb + i + 1];
        unsigned e2 = packed2[rb + i + 2];
        unsigned e3 = packed2[rb + i + 3];
        uint4 g0 = ec[(size_t)e0 * 8];
        uint4 g1 = ec[(size_t)e1 * 8];
        uint4 g2 = ec[(size_t)e2 * 8];
        uint4 g3 = ec[(size_t)e3 * 8];
        a0 = pkmax4(a0, g0);
        a1 = pkmax4(a1, g1);
        a2 = pkmax4(a2, g2);
        a3 = pkmax4(a3, g3);
    }
    for (; i < deg; ++i) {
        unsigned e0 = packed2[rb + i];
        a0 = pkmax4(a0, ec[(size_t)e0 * 8]);
    }
    uint4 m = pkmax4(pkmax4(a0, a1), pkmax4(a2, a3));
    uint4 es = ec[(size_t)n * 8];               // self row (encoded)
    uint4 o;
    o.x = seg_finish2(m.x, es.x);
    o.y = seg_finish2(m.y, es.y);
    o.z = seg_finish2(m.z, es.z);
    o.w = seg_finish2(m.w, es.w);
    agg4[(size_t)n * 8 + col] = o;              // coalesced 1 KB per wave
}

// ---------- pass E: MFMA MLP; A-fragments ks0/1 decoded from nfenc ----------
__global__ __launch_bounds__(256) void node_mlp_mfma(
        const unsigned* __restrict__ nfencu,    // ord-encoded rows, 32 dw/row
        const __bf16* __restrict__ agg16,
        float* __restrict__ out,
        const __bf16* __restrict__ wfrag,
        const float* __restrict__ bias,
        int nTiles, int nN) {
    int lane = threadIdx.x & 63;
    int quad = lane >> 4;
    int l16  = lane & 15;
    int waveGlobal = blockIdx.x * 4 + (threadIdx.x >> 6);
    int nWaves = gridDim.x * 4;

    bf16x8 bfrag[4][4];
    #pragma unroll
    for (int c = 0; c < 4; ++c)
        #pragma unroll
        for (int ks = 0; ks < 4; ++ks)
            bfrag[c][ks] = *(const bf16x8*)(wfrag + ((size_t)((ks * 4 + c) * 64 + lane)) * 8);
    float bv[4];
    #pragma unroll
    for (int c = 0; c < 4; ++c) bv[c] = bias[c * 16 + l16];

    for (int t = waveGlobal; t < nTiles; t += nWaves) {
        int n0 = t * 16;
        int rowA = n0 + l16;
        if (rowA >= nN) rowA = nN - 1;
        const unsigned* nfr = nfencu + (size_t)rowA * 32;
        const __bf16*   agr = agg16  + (size_t)rowA * D;

        floatx4 acc[4] = {{0,0,0,0},{0,0,0,0},{0,0,0,0},{0,0,0,0}};
        #pragma unroll
        for (int ks = 0; ks < 4; ++ks) {
            bf16x8 a;
            if (ks < 2) {
                uint4 w = *(const uint4*)(nfr + ks * 16 + quad * 4);
                w.x = pk_ord_decode(w.x); w.y = pk_ord_decode(w.y);
                w.z = pk_ord_decode(w.z); w.w = pk_ord_decode(w.w);
                a = __builtin_bit_cast(bf16x8, w);
            } else {
                a = *(const bf16x8*)(agr + (ks - 2) * 32 + quad * 8);
            }
            #pragma unroll
            for (int c = 0; c < 4; ++c)
                acc[c] = __builtin_amdgcn_mfma_f32_16x16x32_bf16(
                             a, bfrag[c][ks], acc[c], 0, 0, 0);
        }
        #pragma unroll
        for (int r = 0; r < 4; ++r) {
            int row = n0 + quad * 4 + r;
            if (row < nN) {
                #pragma unroll
                for (int c = 0; c < 4; ++c) {
                    float vv = acc[c][r] + bv[c];
                    out[(size_t)row * D + c * 16 + l16] = fmaxf(vv, 0.0f);
                }
            }
        }
    }
}

extern "C" void kernel_launch(void* const* d_in, const int* in_sizes, int n_in,
                              void* d_out, int out_size, void* d_ws, size_t ws_size,
                              hipStream_t stream) {
    const float* nf  = (const float*)d_in[0];
    const int*   src = (const int*)d_in[1];
    const int*   dst = (const int*)d_in[2];
    const float* W   = (const float*)d_in[3];
    const float* b   = (const float*)d_in[4];
    float* out = (float*)d_out;

    int nN = in_sizes[0] / D;
    int nE = in_sizes[1];
    int nbSB = (nN + SBN - 1) / SBN;            // 196

    // ws layout (nfenc now lives in ws so the MLP can read it while
    // writing d_out; packed2 stays in d_out, consumed by seg before MLP)
    char* wsb = (char*)d_ws;
    size_t nfB  = (((size_t)nN * D * 2) + 255) & ~(size_t)255;  // 12.8 MB
    size_t pkB  = (((size_t)nE * 4)     + 255) & ~(size_t)255;  // 6.4 MB
    unsigned* nfenc  = (unsigned*)wsb;
    __bf16*   agg16  = (__bf16*)(wsb + nfB);
    unsigned* packed1 = (unsigned*)(wsb + 2 * nfB);
    unsigned* ghist  = (unsigned*)(wsb + 2 * nfB + pkB);
    unsigned* base   = (unsigned*)(wsb + 2 * nfB + pkB + 4 * MAXSB);
    unsigned* cursor = (unsigned*)(wsb + 2 * nfB + pkB + 4 * MAXSB + 4 * (MAXSB + 2));
    __bf16*   wfrag  = (__bf16*)(wsb + 2 * nfB + pkB + 4 * MAXSB + 8 * (MAXSB + 2));
    unsigned* nodestart = (unsigned*)(wsb + 2 * nfB + pkB + 4 * MAXSB
                                      + 8 * (MAXSB + 2) + 32768);
    unsigned* packed2 = (unsigned*)d_out;

    hipMemsetAsync(ghist, 0, (size_t)nbSB * 4, stream);

    int n4 = nN * D / 4;                        // 1.6M
    int convBlocks = (n4 + 255) / 256;          // 6250
    int histBlocks = (nE + HCHUNK - 1) / HCHUNK;// 391
    int gridPrep = convBlocks > histBlocks ? convBlocks : histBlocks;
    prep_kernel<<<gridPrep, 256, 0, stream>>>(nf, nfenc, n4, dst, ghist,
                                              nE, nbSB, W, wfrag,
                                              histBlocks, gridPrep - 1);

    scan_sb<<<1, 256, 0, stream>>>(ghist, base, cursor, nbSB);

    int nbS = (nE + SCHUNK - 1) / SCHUNK;       // 391
    sb_scatter<<<nbS, 256, 0, stream>>>(src, dst, cursor, packed1, nE, nbSB);

    sb_sort<<<nbSB, SORT_THREADS, 0, stream>>>(packed1, base, packed2,
                                               nodestart, nN);

    int segBlocks = (nN + 31) / 32;             // 3125: 8 nodes/wave, parallel
    seg_direct<<<segBlocks, 256, 0, stream>>>(
        (const uint4*)nfenc, packed2, nodestart, (uint4*)agg16, nN);

    int nTiles = (nN + 15) / 16;
    node_mlp_mfma<<<768, 256, 0, stream>>>(nfenc, agg16, out, wfrag, b,
                                           nTiles, nN);
}